// Round 10
// baseline (258.285 us; speedup 1.0000x reference)
//
#include <hip/hip_runtime.h>

typedef _Float16 h4 __attribute__((ext_vector_type(4)));
typedef _Float16 h2 __attribute__((ext_vector_type(2)));

// Problem constants (reference: B,M,N,L,S,KERN = 4,256,256,24,22,256; KERN==M → tile is identity)
constexpr int B_ = 4, M_ = 256, N_ = 256, L_ = 24, S_ = 22;
constexpr int SP_  = 24;    // shots padded to 24 (2 zero rows) for clean s-quads
constexpr int AP_  = 257;   // A4 row pitch in h4 units (odd pad; rows 8B-aligned)
constexpr int XP_  = 26;    // xT row pitch in halves (52B rows; 13-dword lane stride, gcd(13,32)=1 -> conflict-free)
constexpr int NYR_ = 280;   // Y rows per (b,sq) plane (279 used)

// Dynamic LDS layout (bytes):
constexpr int A4_BYTES = SP_ * AP_ * 8;           // 49,344
constexpr int XT_BYTES = B_ * N_ * XP_ * 2;       // 53,248
constexpr int Y_BYTES  = B_ * 6 * NYR_ * 8;       // 53,760  ([b][sq][n'] h4 planes: lane-consecutive)
constexpr int WMAX_OFF = A4_BYTES + XT_BYTES + Y_BYTES;  // 156,352 (16B-aligned)
constexpr int LDS_BYTES = WMAX_OFF + 32;                 // 156,384 <= 163,840
constexpr int XT_OFF_H  = A4_BYTES / 2;                  // half-index 24,672
constexpr int Y_OFF_H4  = (A4_BYTES + XT_BYTES) / 8;     // h4-index 12,824

// Color bases as COMPILE-TIME constants (validated R6/R8/R9):
// F_c[l] = exp(-0.5*((400+300*l/23 - mu_c)/50)^2); pairing wr<->620, wg<->550, wb<->450, wc<->500.
constexpr float FR[L_] = {  // mu = 620
    6.252150e-05f, 1.904358e-04f, 5.418690e-04f, 1.440515e-03f, 3.577400e-03f,
    8.299750e-03f, 1.798893e-02f, 3.642490e-02f, 6.890060e-02f, 1.217600e-01f,
    2.010120e-01f, 3.100190e-01f, 4.466857e-01f, 6.012587e-01f, 7.560710e-01f,
    8.881955e-01f, 9.747661e-01f, 9.993953e-01f, 9.572367e-01f, 8.565352e-01f,
    7.160078e-01f, 5.591580e-01f, 4.079402e-01f, 2.780373e-01f};
constexpr float FG[L_] = {  // mu = 550
    1.110900e-02f, 2.348440e-02f, 4.638000e-02f, 8.557090e-02f, 1.474900e-01f,
    2.374920e-01f, 3.572560e-01f, 5.020580e-01f, 6.591400e-01f, 8.084270e-01f,
    9.262975e-01f, 9.915296e-01f, 9.915296e-01f, 9.262975e-01f, 8.084270e-01f,
    6.591400e-01f, 5.020580e-01f, 3.572560e-01f, 2.374920e-01f, 1.474900e-01f,
    8.557090e-02f, 4.638000e-02f, 2.348440e-02f, 1.110900e-02f};
constexpr float FB[L_] = {  // mu = 450 (pairs with wb)
    6.065307e-01f, 7.609727e-01f, 8.919300e-01f, 9.766475e-01f, 9.990553e-01f,
    9.547420e-01f, 8.523698e-01f, 7.109096e-01f, 5.539184e-01f, 4.032022e-01f,
    2.741855e-01f, 1.741852e-01f, 1.033776e-01f, 5.731640e-02f, 2.968800e-02f,
    1.436580e-02f, 6.494090e-03f, 2.742560e-03f, 1.079230e-03f, 3.988070e-04f,
    1.369660e-04f, 4.417250e-05f, 1.327420e-05f, 3.726650e-06f};
constexpr float FC[L_] = {  // mu = 500 (pairs with wc)
    1.353353e-01f, 2.204053e-01f, 3.353338e-01f, 4.766271e-01f, 6.328849e-01f,
    7.850828e-01f, 9.098110e-01f, 9.849909e-01f, 9.962264e-01f, 9.413024e-01f,
    8.308921e-01f, 6.851808e-01f, 5.278508e-01f, 3.798934e-01f, 2.554222e-01f,
    1.604349e-01f, 9.414200e-02f, 5.160780e-02f, 2.642960e-02f, 1.264440e-02f,
    5.651680e-03f, 2.359870e-03f, 9.205430e-04f, 3.354630e-04f};

__device__ __forceinline__ h2 lo4(h4 v) { return __builtin_shufflevector(v, v, 0, 1); }
__device__ __forceinline__ h2 hi4(h4 v) { return __builtin_shufflevector(v, v, 2, 3); }
__device__ __forceinline__ float fdot2(h2 a, h2 b, float c) {
    return __builtin_amdgcn_fdot2(a, b, c, false);
}

// R9 post-mortem: fused 82us, latency-bound at 1 wave/SIMD (VALUBusy 41%,
// LDS-pipe model ~19us, VALU ~25us — both far under 82). R10: 512-thread
// blocks (2 waves/SIMD, work split wave-uniformly: phase A by s-quads,
// phase B by b), Y planes [b][sq][n'] (lane-consecutive h4 — kills the
// 4-way pitch-14 conflicts, 1.24M cycles in R9), and v_dot2_f32_f16 for
// all G-dots and the phase-B s-contraction (2 insts/dot vs ~8).
__global__ __launch_bounds__(512) __attribute__((amdgpu_waves_per_eu(2, 2)))
void cassi_fused(
    const float* __restrict__ x,
    const float* __restrict__ wr, const float* __restrict__ wg,
    const float* __restrict__ wb, const float* __restrict__ wc,
    float* __restrict__ out, float* __restrict__ bmax_out)
{
    extern __shared__ char lds_raw[];
    h4*       A4  = reinterpret_cast<h4*>(lds_raw);
    _Float16* XTh = reinterpret_cast<_Float16*>(lds_raw);   // + XT_OFF_H
    h2*       XH2 = reinterpret_cast<h2*>(lds_raw);
    h4*       Y4  = reinterpret_cast<h4*>(lds_raw);         // + Y_OFF_H4
    float*    wmax = reinterpret_cast<float*>(lds_raw + WMAX_OFF);

    const int t  = threadIdx.x;
    const int tt = t & 255;       // column lane
    const int h  = t >> 8;        // block half (waves 0-3 vs 4-7: wave-uniform)
    const int m  = blockIdx.x;

    // ---- Staging (once per block, 512 threads) ----
    // zero pad rows s=22,23 of A4 (514 h4 entries)
    {
        h4 z; z.x = z.y = z.z = z.w = (_Float16)0.f;
        A4[S_ * AP_ + t] = z;
        if (t < 2 * AP_ - 512) A4[S_ * AP_ + 512 + t] = z;
    }
    // x rows for all 4 b: 2 rows/thread, float4 global reads, h2-packed LDS writes
    #pragma unroll
    for (int rep = 0; rep < 2; ++rep) {
        const int idx = rep * 512 + t;
        const int b = idx >> 8, n = idx & 255;
        const float4* x4 = reinterpret_cast<const float4*>(x + ((b * M_ + m) * N_ + n) * L_);
        const int rowh2 = (XT_OFF_H + (b * N_ + n) * XP_) / 2;   // even base -> exact
        #pragma unroll
        for (int i = 0; i < 6; ++i) {
            const float4 v = x4[i];
            h2 p0; p0.x = (_Float16)v.x; p0.y = (_Float16)v.y;
            h2 p1; p1.x = (_Float16)v.z; p1.y = (_Float16)v.w;
            XH2[rowh2 + 2 * i + 0] = p0;
            XH2[rowh2 + 2 * i + 1] = p1;
        }
    }
    // weights: coalesced, normalized once, half4-packed A4[s][n]
    {
        const float* wrm = wr + m * (N_ * S_);
        const float* wgm = wg + m * (N_ * S_);
        const float* wbm = wb + m * (N_ * S_);
        const float* wcm = wc + m * (N_ * S_);
        #pragma unroll 1
        for (int i = 0; i < 11; ++i) {       // 11*512 = 5632 floats per array
            const int f = i * 512 + t;
            const float r = wrm[f], g = wgm[f], u = wbm[f], v = wcm[f];
            const int n = f / S_, s = f - n * S_;
            const float inv = 1.f / (r + g + u + v);
            h4 p;
            p.x = (_Float16)(r * inv); p.y = (_Float16)(g * inv);
            p.z = (_Float16)(u * inv); p.w = (_Float16)(v * inv);
            A4[s * AP_ + n] = p;
        }
    }
    __syncthreads();

    // ---- Phase A: half h computes s-quads sq = 3h..3h+2, all 4 b.
    // Lane tt: main n'=tt (l<=tt) + tail n'=256+tt (l>tt, only tt<23) via
    // complementarity; mask folded into G so the b-loop is pure FMA.
    #pragma unroll 1
    for (int sqi = 0; sqi < 3; ++sqi) {
        const int sq = 3 * h + sqi;
        const int s0 = 4 * sq;
        float4 aM[4], aT[4];
        #pragma unroll
        for (int b = 0; b < 4; ++b) { aM[b].x=aM[b].y=aM[b].z=aM[b].w=0.f; aT[b]=aM[b]; }
        #pragma unroll
        for (int l = 0; l < L_; ++l) {
            h2 f01; f01.x = (_Float16)FR[l]; f01.y = (_Float16)FG[l];
            h2 f23; f23.x = (_Float16)FB[l]; f23.y = (_Float16)FC[l];
            const bool mn = (l <= tt);
            const int idx = mn ? (tt - l) : (256 + tt - l);
            const float mm = mn ? 1.f : 0.f;
            const int ab = s0 * AP_ + idx;
            const h4 p0 = A4[ab], p1 = A4[ab + AP_], p2 = A4[ab + 2 * AP_], p3 = A4[ab + 3 * AP_];
            const float g0 = fdot2(lo4(p0), f01, fdot2(hi4(p0), f23, 0.f));
            const float g1 = fdot2(lo4(p1), f01, fdot2(hi4(p1), f23, 0.f));
            const float g2 = fdot2(lo4(p2), f01, fdot2(hi4(p2), f23, 0.f));
            const float g3 = fdot2(lo4(p3), f01, fdot2(hi4(p3), f23, 0.f));
            const float gm0 = g0 * mm, gt0 = g0 - gm0;
            const float gm1 = g1 * mm, gt1 = g1 - gm1;
            const float gm2 = g2 * mm, gt2 = g2 - gm2;
            const float gm3 = g3 * mm, gt3 = g3 - gm3;
            #pragma unroll
            for (int b = 0; b < 4; ++b) {
                const float xv = (float)XTh[XT_OFF_H + (b * N_ + idx) * XP_ + l];
                aM[b].x += gm0 * xv; aT[b].x += gt0 * xv;
                aM[b].y += gm1 * xv; aT[b].y += gt1 * xv;
                aM[b].z += gm2 * xv; aT[b].z += gt2 * xv;
                aM[b].w += gm3 * xv; aT[b].w += gt3 * xv;
            }
        }
        #pragma unroll
        for (int b = 0; b < 4; ++b) {
            const int yb = Y_OFF_H4 + (b * 6 + sq) * NYR_;
            h4 pm;
            pm.x = (_Float16)aM[b].x; pm.y = (_Float16)aM[b].y;
            pm.z = (_Float16)aM[b].z; pm.w = (_Float16)aM[b].w;
            Y4[yb + tt] = pm;                       // lane-consecutive h4 write
            if (tt < 23) {
                h4 pt;
                pt.x = (_Float16)aT[b].x; pt.y = (_Float16)aT[b].y;
                pt.z = (_Float16)aT[b].z; pt.w = (_Float16)aT[b].w;
                Y4[yb + 256 + tt] = pt;
            }
        }
    }
    __syncthreads();

    // ---- Phase B: half h computes b = 2h, 2h+1.  X[b,tt,l] = sum_s G*Y.
    // G computed ONCE per (sq,l), then consumed by both b via fdot2 pairs.
    const int b0 = 2 * h;
    float X0[L_], X1[L_];
    #pragma unroll
    for (int l = 0; l < L_; ++l) { X0[l] = 0.f; X1[l] = 0.f; }
    #pragma unroll 1
    for (int sq = 0; sq < 6; ++sq) {
        const int ab = (4 * sq) * AP_ + tt;
        const h4 q0 = A4[ab], q1 = A4[ab + AP_], q2 = A4[ab + 2 * AP_], q3 = A4[ab + 3 * AP_];
        const int y0b = Y_OFF_H4 + ((b0    ) * 6 + sq) * NYR_ + tt;
        const int y1b = Y_OFF_H4 + ((b0 + 1) * 6 + sq) * NYR_ + tt;
        #pragma unroll
        for (int l = 0; l < L_; ++l) {
            h2 f01; f01.x = (_Float16)FR[l]; f01.y = (_Float16)FG[l];
            h2 f23; f23.x = (_Float16)FB[l]; f23.y = (_Float16)FC[l];
            const float g0 = fdot2(lo4(q0), f01, fdot2(hi4(q0), f23, 0.f));
            const float g1 = fdot2(lo4(q1), f01, fdot2(hi4(q1), f23, 0.f));
            const float g2 = fdot2(lo4(q2), f01, fdot2(hi4(q2), f23, 0.f));
            const float g3 = fdot2(lo4(q3), f01, fdot2(hi4(q3), f23, 0.f));
            h2 G01; G01.x = (_Float16)g0; G01.y = (_Float16)g1;
            h2 G23; G23.x = (_Float16)g2; G23.y = (_Float16)g3;
            const h4 ya = Y4[y0b + l];
            const h4 yb = Y4[y1b + l];
            X0[l] = fdot2(G01, lo4(ya), fdot2(G23, hi4(ya), X0[l]));
            X1[l] = fdot2(G01, lo4(yb), fdot2(G23, hi4(yb), X1[l]));
        }
    }

    // Epilogue: store 2 b rows, track max.
    float vmax = 0.f;
    {
        float4* o4 = reinterpret_cast<float4*>(out + ((b0 * M_ + m) * N_ + tt) * L_);
        #pragma unroll
        for (int i = 0; i < 6; ++i) {
            float4 vq;
            vq.x = X0[4*i+0]; vq.y = X0[4*i+1]; vq.z = X0[4*i+2]; vq.w = X0[4*i+3];
            vmax = fmaxf(vmax, fmaxf(fmaxf(vq.x, vq.y), fmaxf(vq.z, vq.w)));
            o4[i] = vq;
        }
        float4* o5 = reinterpret_cast<float4*>(out + (((b0 + 1) * M_ + m) * N_ + tt) * L_);
        #pragma unroll
        for (int i = 0; i < 6; ++i) {
            float4 vq;
            vq.x = X1[4*i+0]; vq.y = X1[4*i+1]; vq.z = X1[4*i+2]; vq.w = X1[4*i+3];
            vmax = fmaxf(vmax, fmaxf(fmaxf(vq.x, vq.y), fmaxf(vq.z, vq.w)));
            o5[i] = vq;
        }
    }

    #pragma unroll
    for (int off = 32; off > 0; off >>= 1)
        vmax = fmaxf(vmax, __shfl_xor(vmax, off, 64));
    if ((t & 63) == 0) wmax[t >> 6] = vmax;
    __syncthreads();
    if (t == 0) {
        float v = wmax[0];
        #pragma unroll
        for (int i = 1; i < 8; ++i) v = fmaxf(v, wmax[i]);
        bmax_out[m] = v;
    }
}

// Normalize; each block re-reduces the 256 per-block maxes itself.
__global__ __launch_bounds__(256) void cassi_norm(float* __restrict__ out,
                                                  const float* __restrict__ bmax)
{
    __shared__ float wm[4];
    const int t = threadIdx.x;
    float v = bmax[t];
    #pragma unroll
    for (int off = 32; off > 0; off >>= 1)
        v = fmaxf(v, __shfl_xor(v, off, 64));
    if ((t & 63) == 0) wm[t >> 6] = v;
    __syncthreads();
    const float inv = 1.f / fmaxf(fmaxf(wm[0], wm[1]), fmaxf(wm[2], wm[3]));
    const int i = (blockIdx.x * 256 + t) * 4;
    float4 q = *reinterpret_cast<float4*>(out + i);
    q.x *= inv; q.y *= inv; q.z *= inv; q.w *= inv;
    *reinterpret_cast<float4*>(out + i) = q;
}

extern "C" void kernel_launch(void* const* d_in, const int* in_sizes, int n_in,
                              void* d_out, int out_size, void* d_ws, size_t ws_size,
                              hipStream_t stream) {
    const float* x  = (const float*)d_in[0];
    const float* wr = (const float*)d_in[1];
    const float* wg = (const float*)d_in[2];
    const float* wb = (const float*)d_in[3];
    const float* wc = (const float*)d_in[4];
    float* out  = (float*)d_out;
    float* bmax = (float*)d_ws;          // 256 per-block maxes

    hipFuncSetAttribute((const void*)cassi_fused,
                        hipFuncAttributeMaxDynamicSharedMemorySize, LDS_BYTES);

    cassi_fused<<<M_, 512, LDS_BYTES, stream>>>(x, wr, wg, wb, wc, out, bmax);
    const int n4blocks = (B_ * M_ * N_ * L_) / 4 / 256;     // 6144, exact
    cassi_norm<<<n4blocks, 256, 0, stream>>>(out, bmax);
}

// Round 11
// 152.976 us; speedup vs baseline: 1.6884x; 1.6884x over previous
//
#include <hip/hip_runtime.h>

typedef _Float16 h8 __attribute__((ext_vector_type(8)));
typedef _Float16 h4 __attribute__((ext_vector_type(4)));
typedef _Float16 h2 __attribute__((ext_vector_type(2)));

// Problem constants (reference: B,M,N,L,S,KERN = 4,256,256,24,22,256; KERN==M → tile is identity)
constexpr int B_ = 4, M_ = 256, N_ = 256, L_ = 24, S_ = 22;
constexpr int SP_  = 24;    // shots padded to 24 (2 zero rows) for clean s-quads
constexpr int AP_  = 257;   // A4 [s][n] row pitch in h4 units (odd -> b64 reads 2-way, free)
constexpr int XTP_ = 25;    // XT [n][l] row pitch in h4 cells (200B rows, 50-dword stride, 2-way free)
constexpr int NYR_ = 280;   // Y rows per (bp,sq) plane (279 used)

// LDS layout (bytes):
constexpr int A4_BYTES = SP_ * AP_ * 8;            // 49,344  A[s][n] h4 over c
constexpr int XT_BYTES = N_ * XTP_ * 8;            // 51,200  x[n][l] h4 over b
constexpr int Y_BYTES  = 2 * 6 * NYR_ * 16;        // 53,760  Y[bp][sq][n'] 16B cells (2 h4: b-even, b-odd)
constexpr int XT_OFF   = A4_BYTES;                 // 49,344
constexpr int Y_OFF    = A4_BYTES + XT_BYTES;      // 100,544 (16B-aligned)
constexpr int WMAX_OFF = Y_OFF + Y_BYTES;          // 154,304
constexpr int LDS_BYTES = WMAX_OFF + 32;           // 154,336 <= 163,840
constexpr int XT_OFF_H4 = XT_OFF / 8;              // 6,168
constexpr int Y_OFF_H4  = Y_OFF / 8;               // 12,568
constexpr int Y_OFF_H8  = Y_OFF / 16;              // 6,284

// Color bases as COMPILE-TIME constants (validated R6/R8/R9/R10):
constexpr float FR[L_] = {  // mu = 620
    6.252150e-05f, 1.904358e-04f, 5.418690e-04f, 1.440515e-03f, 3.577400e-03f,
    8.299750e-03f, 1.798893e-02f, 3.642490e-02f, 6.890060e-02f, 1.217600e-01f,
    2.010120e-01f, 3.100190e-01f, 4.466857e-01f, 6.012587e-01f, 7.560710e-01f,
    8.881955e-01f, 9.747661e-01f, 9.993953e-01f, 9.572367e-01f, 8.565352e-01f,
    7.160078e-01f, 5.591580e-01f, 4.079402e-01f, 2.780373e-01f};
constexpr float FG[L_] = {  // mu = 550
    1.110900e-02f, 2.348440e-02f, 4.638000e-02f, 8.557090e-02f, 1.474900e-01f,
    2.374920e-01f, 3.572560e-01f, 5.020580e-01f, 6.591400e-01f, 8.084270e-01f,
    9.262975e-01f, 9.915296e-01f, 9.915296e-01f, 9.262975e-01f, 8.084270e-01f,
    6.591400e-01f, 5.020580e-01f, 3.572560e-01f, 2.374920e-01f, 1.474900e-01f,
    8.557090e-02f, 4.638000e-02f, 2.348440e-02f, 1.110900e-02f};
constexpr float FB[L_] = {  // mu = 450 (pairs with wb)
    6.065307e-01f, 7.609727e-01f, 8.919300e-01f, 9.766475e-01f, 9.990553e-01f,
    9.547420e-01f, 8.523698e-01f, 7.109096e-01f, 5.539184e-01f, 4.032022e-01f,
    2.741855e-01f, 1.741852e-01f, 1.033776e-01f, 5.731640e-02f, 2.968800e-02f,
    1.436580e-02f, 6.494090e-03f, 2.742560e-03f, 1.079230e-03f, 3.988070e-04f,
    1.369660e-04f, 4.417250e-05f, 1.327420e-05f, 3.726650e-06f};
constexpr float FC[L_] = {  // mu = 500 (pairs with wc)
    1.353353e-01f, 2.204053e-01f, 3.353338e-01f, 4.766271e-01f, 6.328849e-01f,
    7.850828e-01f, 9.098110e-01f, 9.849909e-01f, 9.962264e-01f, 9.413024e-01f,
    8.308921e-01f, 6.851808e-01f, 5.278508e-01f, 3.798934e-01f, 2.554222e-01f,
    1.604349e-01f, 9.414200e-02f, 5.160780e-02f, 2.642960e-02f, 1.264440e-02f,
    5.651680e-03f, 2.359870e-03f, 9.205430e-04f, 3.354630e-04f};

__device__ __forceinline__ float fdot2(h2 a, h2 b, float c) {
    return __builtin_amdgcn_fdot2(a, b, c, false);
}

// R10 post-mortem: 512 threads -> allocator gave 128 VGPR and spilled phase B
// (WRITE_SIZE 344MB vs 25.6MB output = the smoking gun). R11 returns to the
// proven no-spill R9 shape (256 thr, waves_per_eu(1,1), VGPR 256) and adds:
// fdot2 G-dots, G shared across b-pairs in phase B, Y as [bp][sq][n'] 16B
// cells (lane-consecutive b128, one read serves 2 b), x as [n][l] h4-over-b
// cells (144 b64 vs 576 u16 reads), wave-uniform tail specialization
// (only wave 0 pays the tail accumulator cost).
__global__ __launch_bounds__(256) __attribute__((amdgpu_waves_per_eu(1, 1)))
void cassi_fused(
    const float* __restrict__ x,
    const float* __restrict__ wr, const float* __restrict__ wg,
    const float* __restrict__ wb, const float* __restrict__ wc,
    float* __restrict__ out, float* __restrict__ bmax_out)
{
    extern __shared__ char lds_raw[];
    h4* A4  = reinterpret_cast<h4*>(lds_raw);
    h4* XT4 = reinterpret_cast<h4*>(lds_raw) + XT_OFF_H4;
    h4* Y4  = reinterpret_cast<h4*>(lds_raw) + Y_OFF_H4;
    h8* Y8  = reinterpret_cast<h8*>(lds_raw) + Y_OFF_H8;
    float* wmax = reinterpret_cast<float*>(lds_raw + WMAX_OFF);

    const int t = threadIdx.x;
    const int m = blockIdx.x;

    // ---- Staging ----
    // zero A pad rows s=22,23 (2*257 = 514 h4)
    {
        h4 z; z.x = z.y = z.z = z.w = (_Float16)0.f;
        A4[S_ * AP_ + t] = z;
        A4[S_ * AP_ + 256 + t] = z;
        if (t < 2) A4[S_ * AP_ + 512 + t] = z;
    }
    // x: thread t stages column n=t for all 4 b -> XT[n][l] h4{b0,b1,b2,b3}
    {
        const float4* xb0 = reinterpret_cast<const float4*>(x + ((0 * M_ + m) * N_ + t) * L_);
        const float4* xb1 = reinterpret_cast<const float4*>(x + ((1 * M_ + m) * N_ + t) * L_);
        const float4* xb2 = reinterpret_cast<const float4*>(x + ((2 * M_ + m) * N_ + t) * L_);
        const float4* xb3 = reinterpret_cast<const float4*>(x + ((3 * M_ + m) * N_ + t) * L_);
        #pragma unroll
        for (int i = 0; i < 6; ++i) {
            const float4 v0 = xb0[i], v1 = xb1[i], v2 = xb2[i], v3 = xb3[i];
            h4 c0; c0.x=(_Float16)v0.x; c0.y=(_Float16)v1.x; c0.z=(_Float16)v2.x; c0.w=(_Float16)v3.x;
            h4 c1; c1.x=(_Float16)v0.y; c1.y=(_Float16)v1.y; c1.z=(_Float16)v2.y; c1.w=(_Float16)v3.y;
            h4 c2; c2.x=(_Float16)v0.z; c2.y=(_Float16)v1.z; c2.z=(_Float16)v2.z; c2.w=(_Float16)v3.z;
            h4 c3; c3.x=(_Float16)v0.w; c3.y=(_Float16)v1.w; c3.z=(_Float16)v2.w; c3.w=(_Float16)v3.w;
            XT4[t * XTP_ + 4 * i + 0] = c0;
            XT4[t * XTP_ + 4 * i + 1] = c1;
            XT4[t * XTP_ + 4 * i + 2] = c2;
            XT4[t * XTP_ + 4 * i + 3] = c3;
        }
    }
    // weights: coalesced, normalized once, h4-packed A[s][n]
    {
        const float* wrm = wr + m * (N_ * S_);
        const float* wgm = wg + m * (N_ * S_);
        const float* wbm = wb + m * (N_ * S_);
        const float* wcm = wc + m * (N_ * S_);
        #pragma unroll 1
        for (int i = 0; i < S_; ++i) {
            const int f = i * 256 + t;
            const float r = wrm[f], g = wgm[f], u = wbm[f], v = wcm[f];
            const int n = f / S_, s = f - n * S_;
            const float inv = 1.f / (r + g + u + v);
            h4 p;
            p.x = (_Float16)(r * inv); p.y = (_Float16)(g * inv);
            p.z = (_Float16)(u * inv); p.w = (_Float16)(v * inv);
            A4[s * AP_ + n] = p;
        }
    }
    __syncthreads();

    // ---- Phase A: Y[b][n'][s-quad] gather. Wave 0 (contains tail lanes
    // tt<23) runs the dual main+tail version; waves 1-3 run the lean version
    // (idx = t-l always valid since t >= 64 > 23). Wave-uniform branch.
    if (t < 64) {
        #pragma unroll 1
        for (int sq = 0; sq < 6; ++sq) {
            float4 aM[4], aT[4];
            #pragma unroll
            for (int b = 0; b < 4; ++b) { aM[b].x=aM[b].y=aM[b].z=aM[b].w=0.f; aT[b]=aM[b]; }
            #pragma unroll
            for (int l = 0; l < L_; ++l) {
                h2 f01; f01.x = (_Float16)FR[l]; f01.y = (_Float16)FG[l];
                h2 f23; f23.x = (_Float16)FB[l]; f23.y = (_Float16)FC[l];
                const bool mn = (l <= t);
                const int idx = mn ? (t - l) : (256 + t - l);
                const float mm = mn ? 1.f : 0.f;
                const int ab = (4 * sq) * AP_ + idx;
                const h4 p0 = A4[ab], p1 = A4[ab + AP_], p2 = A4[ab + 2 * AP_], p3 = A4[ab + 3 * AP_];
                const h4 xq = XT4[idx * XTP_ + l];
                const float g0 = fdot2(h2{p0.x,p0.y}, f01, fdot2(h2{p0.z,p0.w}, f23, 0.f));
                const float g1 = fdot2(h2{p1.x,p1.y}, f01, fdot2(h2{p1.z,p1.w}, f23, 0.f));
                const float g2 = fdot2(h2{p2.x,p2.y}, f01, fdot2(h2{p2.z,p2.w}, f23, 0.f));
                const float g3 = fdot2(h2{p3.x,p3.y}, f01, fdot2(h2{p3.z,p3.w}, f23, 0.f));
                const float gm0 = g0 * mm, gt0 = g0 - gm0;
                const float gm1 = g1 * mm, gt1 = g1 - gm1;
                const float gm2 = g2 * mm, gt2 = g2 - gm2;
                const float gm3 = g3 * mm, gt3 = g3 - gm3;
                const float xv[4] = {(float)xq.x, (float)xq.y, (float)xq.z, (float)xq.w};
                #pragma unroll
                for (int b = 0; b < 4; ++b) {
                    aM[b].x += gm0 * xv[b]; aT[b].x += gt0 * xv[b];
                    aM[b].y += gm1 * xv[b]; aT[b].y += gt1 * xv[b];
                    aM[b].z += gm2 * xv[b]; aT[b].z += gt2 * xv[b];
                    aM[b].w += gm3 * xv[b]; aT[b].w += gt3 * xv[b];
                }
            }
            #pragma unroll
            for (int b = 0; b < 4; ++b) {
                const int cell = ((b >> 1) * 6 + sq) * NYR_;
                h4 pm;
                pm.x=(_Float16)aM[b].x; pm.y=(_Float16)aM[b].y;
                pm.z=(_Float16)aM[b].z; pm.w=(_Float16)aM[b].w;
                Y4[(cell + t) * 2 + (b & 1)] = pm;
                if (t < 23) {
                    h4 pt;
                    pt.x=(_Float16)aT[b].x; pt.y=(_Float16)aT[b].y;
                    pt.z=(_Float16)aT[b].z; pt.w=(_Float16)aT[b].w;
                    Y4[(cell + 256 + t) * 2 + (b & 1)] = pt;
                }
            }
        }
    } else {
        #pragma unroll 1
        for (int sq = 0; sq < 6; ++sq) {
            float4 aM[4];
            #pragma unroll
            for (int b = 0; b < 4; ++b) { aM[b].x=aM[b].y=aM[b].z=aM[b].w=0.f; }
            #pragma unroll
            for (int l = 0; l < L_; ++l) {
                h2 f01; f01.x = (_Float16)FR[l]; f01.y = (_Float16)FG[l];
                h2 f23; f23.x = (_Float16)FB[l]; f23.y = (_Float16)FC[l];
                const int idx = t - l;      // t >= 64 -> always >= 41
                const int ab = (4 * sq) * AP_ + idx;
                const h4 p0 = A4[ab], p1 = A4[ab + AP_], p2 = A4[ab + 2 * AP_], p3 = A4[ab + 3 * AP_];
                const h4 xq = XT4[idx * XTP_ + l];
                const float g0 = fdot2(h2{p0.x,p0.y}, f01, fdot2(h2{p0.z,p0.w}, f23, 0.f));
                const float g1 = fdot2(h2{p1.x,p1.y}, f01, fdot2(h2{p1.z,p1.w}, f23, 0.f));
                const float g2 = fdot2(h2{p2.x,p2.y}, f01, fdot2(h2{p2.z,p2.w}, f23, 0.f));
                const float g3 = fdot2(h2{p3.x,p3.y}, f01, fdot2(h2{p3.z,p3.w}, f23, 0.f));
                const float xv[4] = {(float)xq.x, (float)xq.y, (float)xq.z, (float)xq.w};
                #pragma unroll
                for (int b = 0; b < 4; ++b) {
                    aM[b].x += g0 * xv[b];
                    aM[b].y += g1 * xv[b];
                    aM[b].z += g2 * xv[b];
                    aM[b].w += g3 * xv[b];
                }
            }
            #pragma unroll
            for (int b = 0; b < 4; ++b) {
                const int cell = ((b >> 1) * 6 + sq) * NYR_;
                h4 pm;
                pm.x=(_Float16)aM[b].x; pm.y=(_Float16)aM[b].y;
                pm.z=(_Float16)aM[b].z; pm.w=(_Float16)aM[b].w;
                Y4[(cell + t) * 2 + (b & 1)] = pm;
            }
        }
    }
    __syncthreads();

    // ---- Phase B: b-pairs. X[b,t,l] = sum_s G(t,l,s)*Y[b,t+l,s].
    // One lane-consecutive b128 Y read serves both b of the pair; G computed
    // once per (sq,l), packed fp16, consumed by 4 fdot2.
    float vmax = 0.f;
    #pragma unroll 1
    for (int bp = 0; bp < 2; ++bp) {
        float X0[L_], X1[L_];
        #pragma unroll
        for (int l = 0; l < L_; ++l) { X0[l] = 0.f; X1[l] = 0.f; }
        #pragma unroll 1
        for (int sq = 0; sq < 6; ++sq) {
            const int ab = (4 * sq) * AP_ + t;
            const h4 q0 = A4[ab], q1 = A4[ab + AP_], q2 = A4[ab + 2 * AP_], q3 = A4[ab + 3 * AP_];
            const int ybase = (bp * 6 + sq) * NYR_ + t;
            #pragma unroll
            for (int l = 0; l < L_; ++l) {
                h2 f01; f01.x = (_Float16)FR[l]; f01.y = (_Float16)FG[l];
                h2 f23; f23.x = (_Float16)FB[l]; f23.y = (_Float16)FC[l];
                const float g0 = fdot2(h2{q0.x,q0.y}, f01, fdot2(h2{q0.z,q0.w}, f23, 0.f));
                const float g1 = fdot2(h2{q1.x,q1.y}, f01, fdot2(h2{q1.z,q1.w}, f23, 0.f));
                const float g2 = fdot2(h2{q2.x,q2.y}, f01, fdot2(h2{q2.z,q2.w}, f23, 0.f));
                const float g3 = fdot2(h2{q3.x,q3.y}, f01, fdot2(h2{q3.z,q3.w}, f23, 0.f));
                h2 G01; G01.x = (_Float16)g0; G01.y = (_Float16)g1;
                h2 G23; G23.x = (_Float16)g2; G23.y = (_Float16)g3;
                const h8 y = Y8[ybase + l];
                X0[l] = fdot2(G01, h2{y[0],y[1]}, fdot2(G23, h2{y[2],y[3]}, X0[l]));
                X1[l] = fdot2(G01, h2{y[4],y[5]}, fdot2(G23, h2{y[6],y[7]}, X1[l]));
            }
        }
        float4* o0 = reinterpret_cast<float4*>(out + (((2*bp    ) * M_ + m) * N_ + t) * L_);
        float4* o1 = reinterpret_cast<float4*>(out + (((2*bp + 1) * M_ + m) * N_ + t) * L_);
        #pragma unroll
        for (int i = 0; i < 6; ++i) {
            float4 v0, v1;
            v0.x = X0[4*i+0]; v0.y = X0[4*i+1]; v0.z = X0[4*i+2]; v0.w = X0[4*i+3];
            v1.x = X1[4*i+0]; v1.y = X1[4*i+1]; v1.z = X1[4*i+2]; v1.w = X1[4*i+3];
            vmax = fmaxf(vmax, fmaxf(fmaxf(v0.x, v0.y), fmaxf(v0.z, v0.w)));
            vmax = fmaxf(vmax, fmaxf(fmaxf(v1.x, v1.y), fmaxf(v1.z, v1.w)));
            o0[i] = v0;
            o1[i] = v1;
        }
    }

    #pragma unroll
    for (int off = 32; off > 0; off >>= 1)
        vmax = fmaxf(vmax, __shfl_xor(vmax, off, 64));
    if ((t & 63) == 0) wmax[t >> 6] = vmax;
    __syncthreads();
    if (t == 0)
        bmax_out[m] = fmaxf(fmaxf(wmax[0], wmax[1]), fmaxf(wmax[2], wmax[3]));
}

// Normalize; each block re-reduces the 256 per-block maxes itself.
__global__ __launch_bounds__(256) void cassi_norm(float* __restrict__ out,
                                                  const float* __restrict__ bmax)
{
    __shared__ float wm[4];
    const int t = threadIdx.x;
    float v = bmax[t];
    #pragma unroll
    for (int off = 32; off > 0; off >>= 1)
        v = fmaxf(v, __shfl_xor(v, off, 64));
    if ((t & 63) == 0) wm[t >> 6] = v;
    __syncthreads();
    const float inv = 1.f / fmaxf(fmaxf(wm[0], wm[1]), fmaxf(wm[2], wm[3]));
    const int i = (blockIdx.x * 256 + t) * 4;
    float4 q = *reinterpret_cast<float4*>(out + i);
    q.x *= inv; q.y *= inv; q.z *= inv; q.w *= inv;
    *reinterpret_cast<float4*>(out + i) = q;
}

extern "C" void kernel_launch(void* const* d_in, const int* in_sizes, int n_in,
                              void* d_out, int out_size, void* d_ws, size_t ws_size,
                              hipStream_t stream) {
    const float* x  = (const float*)d_in[0];
    const float* wr = (const float*)d_in[1];
    const float* wg = (const float*)d_in[2];
    const float* wb = (const float*)d_in[3];
    const float* wc = (const float*)d_in[4];
    float* out  = (float*)d_out;
    float* bmax = (float*)d_ws;          // 256 per-block maxes

    hipFuncSetAttribute((const void*)cassi_fused,
                        hipFuncAttributeMaxDynamicSharedMemorySize, LDS_BYTES);

    cassi_fused<<<M_, 256, LDS_BYTES, stream>>>(x, wr, wg, wb, wc, out, bmax);
    const int n4blocks = (B_ * M_ * N_ * L_) / 4 / 256;     // 6144, exact
    cassi_norm<<<n4blocks, 256, 0, stream>>>(out, bmax);
}